// Round 5
// baseline (593.391 us; speedup 1.0000x reference)
//
#include <hip/hip_runtime.h>

// DicepolyTopk: dice loss + mean of top-10% poly1-BCE values over N=16.7M fp32.
// Histogram selection on float bit patterns (poly1 >= 0 -> bits order-preserving).
// R5: fuse 6 dispatches -> 3. Each big pass ends with a device-scope arrival
// counter; the LAST block to arrive runs the selection (and finalize in K2)
// inline, reading cross-block data with agent-scope atomic loads. Layer-2
// refinement uses 2048 bins (16 KB LDS -> 8 blocks/CU, exact fit at grid 2048).

#define NBINS1 4096
#define NBINS2 2048
#define NREP1 16
#define NREP2 4
#define GRID 2048
#define BLK 256
#define POLY_EPS 3.1f
#define LN2F 0.69314718056f

struct Ctl {
  unsigned int b1;    // L1 bucket containing the k-th largest value
  unsigned int r;     // k - count(strictly greater L1 buckets)
  unsigned int cnt1;  // arrival counter kernel 1
  unsigned int cnt2;  // arrival counter kernel 2
};

// bce in log2 domain: a2=log2(p), b2=log2(1-p); bce2 = -(b2 + t*(a2-b2))
// bce = bce2*ln2 ; pt = 2^(-bce2) ; poly1 = bce + (1-pt)*eps, clamped >= 0.
// Must be bit-identical between K1 and K2 (same code, deterministic).
__device__ __forceinline__ float poly1_val(float p, float t) {
  float a2 = __builtin_amdgcn_logf(p);         // v_log_f32: log2(p)
  float b2 = __builtin_amdgcn_logf(1.0f - p);  // log2(1-p)
  float bce2 = -(b2 + t * (a2 - b2));
  float pt = __builtin_amdgcn_exp2f(-bce2);    // v_exp_f32: 2^(-bce2)
  float v = bce2 * LN2F + (1.0f - pt) * POLY_EPS;
  return v > 0.0f ? v : 0.0f;
}

__device__ __forceinline__ unsigned int aload_u32(const unsigned int* p) {
  return __hip_atomic_load(p, __ATOMIC_RELAXED, __HIP_MEMORY_SCOPE_AGENT);
}
__device__ __forceinline__ float aload_f32(const float* p) {
  return __hip_atomic_load(p, __ATOMIC_RELAXED, __HIP_MEMORY_SCOPE_AGENT);
}
__device__ __forceinline__ double aload_f64(const double* p) {
  return __hip_atomic_load(p, __ATOMIC_RELAXED, __HIP_MEMORY_SCOPE_AGENT);
}

// ============ K1: dice sums + L1 histogram + (last block) select1 ==========
__global__ void __launch_bounds__(BLK, 8) k1_kernel(
    const float* __restrict__ preds, const float* __restrict__ gts,
    long long n, Ctl* ctl, double* __restrict__ blockSums,
    unsigned int* __restrict__ hist1R, unsigned int K) {
  __shared__ unsigned int h[NBINS1];
  __shared__ double wred[4][3];
  __shared__ unsigned int sflag;
  for (int i = threadIdx.x; i < NBINS1; i += BLK) h[i] = 0u;
  __syncthreads();

  float I = 0.f, Sp = 0.f, St = 0.f;
  long long n4 = n >> 2;
  const float4* p4 = (const float4*)preds;
  const float4* t4 = (const float4*)gts;
  long long stride = (long long)gridDim.x * BLK;
  long long i0 = (long long)blockIdx.x * BLK + threadIdx.x;

  for (long long i = i0; i < n4; i += stride) {
    float4 p = p4[i];
    float4 t = t4[i];
    float ps[4] = {p.x, p.y, p.z, p.w};
    float ts[4] = {t.x, t.y, t.z, t.w};
#pragma unroll
    for (int j = 0; j < 4; ++j) {
      float pp = ps[j], tt = ts[j];
      I += pp * tt;
      Sp += pp;
      St += tt;
      float v = poly1_val(pp, tt);
      atomicAdd(&h[__float_as_uint(v) >> 19], 1u);
    }
  }
  for (long long i = (n4 << 2) + i0; i < n; i += stride) {
    float pp = preds[i], tt = gts[i];
    I += pp * tt; Sp += pp; St += tt;
    float v = poly1_val(pp, tt);
    atomicAdd(&h[__float_as_uint(v) >> 19], 1u);
  }

  // block dice reduce -> one plain store (consumed next dispatch, no atomics)
  double dI = I, dSp = Sp, dSt = St;
#pragma unroll
  for (int off = 32; off; off >>= 1) {
    dI += __shfl_down(dI, off, 64);
    dSp += __shfl_down(dSp, off, 64);
    dSt += __shfl_down(dSt, off, 64);
  }
  if ((threadIdx.x & 63) == 0) {
    int w = threadIdx.x >> 6;
    wred[w][0] = dI; wred[w][1] = dSp; wred[w][2] = dSt;
  }
  __syncthreads();
  if (threadIdx.x == 0) {
    double a = 0, b = 0, c = 0;
#pragma unroll
    for (int w = 0; w < 4; ++w) { a += wred[w][0]; b += wred[w][1]; c += wred[w][2]; }
    blockSums[blockIdx.x * 3 + 0] = a;
    blockSums[blockIdx.x * 3 + 1] = b;
    blockSums[blockIdx.x * 3 + 2] = c;
  }

  // flush LDS hist to one of NREP1 replicas (device-scope atomics)
  unsigned int* dst = hist1R + (size_t)(blockIdx.x & (NREP1 - 1)) * NBINS1;
  for (int i = threadIdx.x; i < NBINS1; i += BLK) {
    unsigned c = h[i];
    if (c) atomicAdd(&dst[i], c);
  }

  // arrival: last block runs select1
  __threadfence();
  __syncthreads();
  if (threadIdx.x == 0) {
    unsigned old = __hip_atomic_fetch_add(&ctl->cnt1, 1u, __ATOMIC_ACQ_REL,
                                          __HIP_MEMORY_SCOPE_AGENT);
    sflag = (old == gridDim.x - 1) ? 1u : 0u;
  }
  __syncthreads();
  if (!sflag) return;

  // ---- select1 (256 threads, 16 bins/thread) ----
  int t = threadIdx.x;
  unsigned hl[16];
  unsigned tot = 0;
#pragma unroll
  for (int j = 0; j < 16; ++j) {
    unsigned s = 0;
    for (int r = 0; r < NREP1; ++r)
      s += aload_u32(&hist1R[(size_t)r * NBINS1 + t * 16 + j]);
    hl[j] = s;
    tot += s;
  }
  __syncthreads();
  h[t] = tot;  // reuse h[0..255] as chunk totals
  __syncthreads();
  for (int off = 1; off < 256; off <<= 1) {  // inclusive suffix scan
    unsigned add = (t + off < 256) ? h[t + off] : 0u;
    __syncthreads();
    h[t] += add;
    __syncthreads();
  }
  unsigned above = (t < 255) ? h[t + 1] : 0u;
  unsigned cum = above;
  for (int j = 15; j >= 0; --j) {
    unsigned nc = cum + hl[j];
    if (cum < K && nc >= K) {  // exactly one (t,j) satisfies globally
      ctl->b1 = (unsigned)(t * 16 + j);
      ctl->r = K - cum;
    }
    cum = nc;
  }
}

// ====== K2: Sgt + refine within b1 + (last block) select2 + finalize =======
__global__ void __launch_bounds__(BLK, 8) k2_kernel(
    const float* __restrict__ preds, const float* __restrict__ gts,
    long long n, Ctl* ctl, const double* __restrict__ blockSums,
    double* __restrict__ blockSgt, unsigned int* __restrict__ hist2R,
    float* __restrict__ sum2R, float* __restrict__ out, unsigned int K) {
  __shared__ unsigned int h2[NBINS2];
  __shared__ float s2[NBINS2];
  __shared__ double wred[4];
  __shared__ unsigned int sflag, sb2, sr2;
  __shared__ double db2sum, db2cnt;
  __shared__ double red5[4][5];
  for (int i = threadIdx.x; i < NBINS2; i += BLK) { h2[i] = 0u; s2[i] = 0.f; }
  __syncthreads();

  unsigned b1 = ctl->b1;  // written last dispatch: plain load fine
  double sgt = 0.0;
  long long n4 = n >> 2;
  const float4* p4 = (const float4*)preds;
  const float4* t4 = (const float4*)gts;
  long long stride = (long long)gridDim.x * BLK;
  long long i0 = (long long)blockIdx.x * BLK + threadIdx.x;

  for (long long i = i0; i < n4; i += stride) {
    float4 p = p4[i];
    float4 t = t4[i];
    float ps[4] = {p.x, p.y, p.z, p.w};
    float ts[4] = {t.x, t.y, t.z, t.w};
#pragma unroll
    for (int j = 0; j < 4; ++j) {
      float v = poly1_val(ps[j], ts[j]);
      unsigned u = __float_as_uint(v);
      unsigned b = u >> 19;
      if (b > b1) {
        sgt += (double)v;
      } else if (b == b1) {
        unsigned key = (u >> 8) & (NBINS2 - 1);  // bits 18:8
        atomicAdd(&h2[key], 1u);
        atomicAdd(&s2[key], v);
      }
    }
  }
  for (long long i = (n4 << 2) + i0; i < n; i += stride) {
    float v = poly1_val(preds[i], gts[i]);
    unsigned u = __float_as_uint(v);
    unsigned b = u >> 19;
    if (b > b1) {
      sgt += (double)v;
    } else if (b == b1) {
      unsigned key = (u >> 8) & (NBINS2 - 1);
      atomicAdd(&h2[key], 1u);
      atomicAdd(&s2[key], v);
    }
  }

#pragma unroll
  for (int off = 32; off; off >>= 1) sgt += __shfl_down(sgt, off, 64);
  if ((threadIdx.x & 63) == 0) wred[threadIdx.x >> 6] = sgt;
  __syncthreads();
  if (threadIdx.x == 0) {
    double v = wred[0] + wred[1] + wred[2] + wred[3];
    // consumed by last block THIS dispatch -> agent-scope atomic store
    __hip_atomic_store(&blockSgt[blockIdx.x], v, __ATOMIC_RELAXED,
                       __HIP_MEMORY_SCOPE_AGENT);
  }

  unsigned int* hd = hist2R + (size_t)(blockIdx.x & (NREP2 - 1)) * NBINS2;
  float* sd = sum2R + (size_t)(blockIdx.x & (NREP2 - 1)) * NBINS2;
  for (int i = threadIdx.x; i < NBINS2; i += BLK) {
    unsigned c = h2[i];
    if (c) atomicAdd(&hd[i], c);
    float sv = s2[i];
    if (sv != 0.f) atomicAdd(&sd[i], sv);
  }

  __threadfence();
  __syncthreads();
  if (threadIdx.x == 0) {
    unsigned old = __hip_atomic_fetch_add(&ctl->cnt2, 1u, __ATOMIC_ACQ_REL,
                                          __HIP_MEMORY_SCOPE_AGENT);
    sflag = (old == gridDim.x - 1) ? 1u : 0u;
  }
  __syncthreads();
  if (!sflag) return;

  // ---- select2 + finalize (256 threads, 8 bins/thread) ----
  int t = threadIdx.x;
  unsigned Kr = ctl->r;
  unsigned hl[8];
  float sl[8];
  unsigned tot = 0;
#pragma unroll
  for (int j = 0; j < 8; ++j) {
    unsigned hs = 0;
    float ss = 0.f;
    for (int r = 0; r < NREP2; ++r) {
      hs += aload_u32(&hist2R[(size_t)r * NBINS2 + t * 8 + j]);
      ss += aload_f32(&sum2R[(size_t)r * NBINS2 + t * 8 + j]);
    }
    hl[j] = hs;
    sl[j] = ss;
    tot += hs;
  }
  __syncthreads();
  h2[t] = tot;  // reuse h2[0..255] as chunk totals
  __syncthreads();
  for (int off = 1; off < 256; off <<= 1) {
    unsigned add = (t + off < 256) ? h2[t + off] : 0u;
    __syncthreads();
    h2[t] += add;
    __syncthreads();
  }
  unsigned above = (t < 255) ? h2[t + 1] : 0u;
  unsigned cum = above;
  for (int j = 7; j >= 0; --j) {
    unsigned nc = cum + hl[j];
    if (cum < Kr && nc >= Kr) {
      sb2 = (unsigned)(t * 8 + j);
      sr2 = Kr - cum;
    }
    cum = nc;
  }
  __syncthreads();
  unsigned b2 = sb2;
  unsigned r2 = sr2;

  double loc = 0.0;
#pragma unroll
  for (int j = 0; j < 8; ++j) {
    int bin = t * 8 + j;
    if (bin > (int)b2) loc += (double)sl[j];
    if (bin == (int)b2) { db2sum = (double)sl[j]; db2cnt = (double)hl[j]; }
  }

  // gather dice partials (prev dispatch: plain loads) + Sgt (this dispatch:
  // agent atomic loads)
  double I = 0, Sp = 0, St = 0, Sg = 0;
  for (int i = t; i < GRID; i += BLK) {
    I += blockSums[i * 3 + 0];
    Sp += blockSums[i * 3 + 1];
    St += blockSums[i * 3 + 2];
    Sg += aload_f64(&blockSgt[i]);
  }
#pragma unroll
  for (int off = 32; off; off >>= 1) {
    loc += __shfl_down(loc, off, 64);
    I += __shfl_down(I, off, 64);
    Sp += __shfl_down(Sp, off, 64);
    St += __shfl_down(St, off, 64);
    Sg += __shfl_down(Sg, off, 64);
  }
  if ((t & 63) == 0) {
    int w = t >> 6;
    red5[w][0] = loc; red5[w][1] = I; red5[w][2] = Sp; red5[w][3] = St;
    red5[w][4] = Sg;
  }
  __syncthreads();
  if (t == 0) {
    double S2 = 0, tI = 0, tSp = 0, tSt = 0, tSg = 0;
#pragma unroll
    for (int w = 0; w < 4; ++w) {
      S2 += red5[w][0]; tI += red5[w][1]; tSp += red5[w][2];
      tSt += red5[w][3]; tSg += red5[w][4];
    }
    // ties in sub-bucket b2 span < 256 ulps: bin average for the r2 remaining
    double avg = db2sum / db2cnt;
    double dice = 1.0 - (2.0 * tI + 1.0) / (tSp + tSt + 1.0);
    double mean_topk = (tSg + S2 + (double)r2 * avg) / (double)K;
    out[0] = (float)(dice + mean_topk);
  }
}

extern "C" void kernel_launch(void* const* d_in, const int* in_sizes, int n_in,
                              void* d_out, int out_size, void* d_ws,
                              size_t ws_size, hipStream_t stream) {
  const float* preds = (const float*)d_in[0];
  const float* gts = (const float*)d_in[1];
  long long n = (long long)in_sizes[0];
  unsigned int K = (unsigned int)(n * 10 / 100);  // matches int(N*10/100)

  char* ws = (char*)d_ws;
  Ctl* ctl = (Ctl*)ws;                                   // @0       (256 B slot)
  double* blockSums = (double*)(ws + 256);               // GRID*3 f64 = 49152
  double* blockSgt = (double*)(ws + 49408);              // GRID f64   = 16384
  unsigned int* hist1R = (unsigned int*)(ws + 65792);    // 16*4096 u32 = 262144
  unsigned int* hist2R = (unsigned int*)(ws + 327936);   // 4*2048 u32  = 32768
  float* sum2R = (float*)(ws + 360704);                  // 4*2048 f32  = 32768
  size_t used = 393472;

  (void)hipMemsetAsync(d_ws, 0, used, stream);

  k1_kernel<<<GRID, BLK, 0, stream>>>(preds, gts, n, ctl, blockSums, hist1R, K);
  k2_kernel<<<GRID, BLK, 0, stream>>>(preds, gts, n, ctl, blockSums, blockSgt,
                                      hist2R, sum2R, (float*)d_out, K);
}

// Round 6
// 561.666 us; speedup vs baseline: 1.0565x; 1.0565x over previous
//
#include <hip/hip_runtime.h>

// DicepolyTopk: dice loss + mean of top-10% poly1-BCE values over N=16.7M fp32.
// Histogram selection on float bit patterns (poly1 >= 0 -> bits order-preserving).
// R6: R5's fused 2-dispatch structure, but WITHOUT the min-waves launch bound.
// R5's __launch_bounds__(256,8) squeezed VGPRs to 28 -> serialized loads, 6x
// regression. Let the compiler allocate freely (R4 ran fast at VGPR 44-52).

#define NBINS1 4096
#define NBINS2 2048
#define NREP1 16
#define NREP2 4
#define GRID 2048
#define BLK 256
#define POLY_EPS 3.1f
#define LN2F 0.69314718056f

struct Ctl {
  unsigned int b1;    // L1 bucket containing the k-th largest value
  unsigned int r;     // k - count(strictly greater L1 buckets)
  unsigned int cnt1;  // arrival counter kernel 1
  unsigned int cnt2;  // arrival counter kernel 2
};

// bce in log2 domain: a2=log2(p), b2=log2(1-p); bce2 = -(b2 + t*(a2-b2))
// bce = bce2*ln2 ; pt = 2^(-bce2) ; poly1 = bce + (1-pt)*eps, clamped >= 0.
// Must be bit-identical between K1 and K2 (same code, deterministic).
__device__ __forceinline__ float poly1_val(float p, float t) {
  float a2 = __builtin_amdgcn_logf(p);         // v_log_f32: log2(p)
  float b2 = __builtin_amdgcn_logf(1.0f - p);  // log2(1-p)
  float bce2 = -(b2 + t * (a2 - b2));
  float pt = __builtin_amdgcn_exp2f(-bce2);    // v_exp_f32: 2^(-bce2)
  float v = bce2 * LN2F + (1.0f - pt) * POLY_EPS;
  return v > 0.0f ? v : 0.0f;
}

__device__ __forceinline__ unsigned int aload_u32(const unsigned int* p) {
  return __hip_atomic_load(p, __ATOMIC_RELAXED, __HIP_MEMORY_SCOPE_AGENT);
}
__device__ __forceinline__ float aload_f32(const float* p) {
  return __hip_atomic_load(p, __ATOMIC_RELAXED, __HIP_MEMORY_SCOPE_AGENT);
}
__device__ __forceinline__ double aload_f64(const double* p) {
  return __hip_atomic_load(p, __ATOMIC_RELAXED, __HIP_MEMORY_SCOPE_AGENT);
}

// ============ K1: dice sums + L1 histogram + (last block) select1 ==========
__global__ void __launch_bounds__(BLK) k1_kernel(
    const float* __restrict__ preds, const float* __restrict__ gts,
    long long n, Ctl* ctl, double* __restrict__ blockSums,
    unsigned int* __restrict__ hist1R, unsigned int K) {
  __shared__ unsigned int h[NBINS1];
  __shared__ double wred[4][3];
  __shared__ unsigned int sflag;
  for (int i = threadIdx.x; i < NBINS1; i += BLK) h[i] = 0u;
  __syncthreads();

  float I = 0.f, Sp = 0.f, St = 0.f;
  long long n4 = n >> 2;
  const float4* p4 = (const float4*)preds;
  const float4* t4 = (const float4*)gts;
  long long stride = (long long)gridDim.x * BLK;
  long long i0 = (long long)blockIdx.x * BLK + threadIdx.x;

  for (long long i = i0; i < n4; i += stride) {
    float4 p = p4[i];
    float4 t = t4[i];
    float ps[4] = {p.x, p.y, p.z, p.w};
    float ts[4] = {t.x, t.y, t.z, t.w};
#pragma unroll
    for (int j = 0; j < 4; ++j) {
      float pp = ps[j], tt = ts[j];
      I += pp * tt;
      Sp += pp;
      St += tt;
      float v = poly1_val(pp, tt);
      atomicAdd(&h[__float_as_uint(v) >> 19], 1u);
    }
  }
  for (long long i = (n4 << 2) + i0; i < n; i += stride) {
    float pp = preds[i], tt = gts[i];
    I += pp * tt; Sp += pp; St += tt;
    float v = poly1_val(pp, tt);
    atomicAdd(&h[__float_as_uint(v) >> 19], 1u);
  }

  // block dice reduce -> one plain store (consumed next dispatch, no atomics)
  double dI = I, dSp = Sp, dSt = St;
#pragma unroll
  for (int off = 32; off; off >>= 1) {
    dI += __shfl_down(dI, off, 64);
    dSp += __shfl_down(dSp, off, 64);
    dSt += __shfl_down(dSt, off, 64);
  }
  if ((threadIdx.x & 63) == 0) {
    int w = threadIdx.x >> 6;
    wred[w][0] = dI; wred[w][1] = dSp; wred[w][2] = dSt;
  }
  __syncthreads();
  if (threadIdx.x == 0) {
    double a = 0, b = 0, c = 0;
#pragma unroll
    for (int w = 0; w < 4; ++w) { a += wred[w][0]; b += wred[w][1]; c += wred[w][2]; }
    blockSums[blockIdx.x * 3 + 0] = a;
    blockSums[blockIdx.x * 3 + 1] = b;
    blockSums[blockIdx.x * 3 + 2] = c;
  }

  // flush LDS hist to one of NREP1 replicas (device-scope atomics)
  unsigned int* dst = hist1R + (size_t)(blockIdx.x & (NREP1 - 1)) * NBINS1;
  for (int i = threadIdx.x; i < NBINS1; i += BLK) {
    unsigned c = h[i];
    if (c) atomicAdd(&dst[i], c);
  }

  // arrival: last block runs select1
  __threadfence();
  __syncthreads();
  if (threadIdx.x == 0) {
    unsigned old = __hip_atomic_fetch_add(&ctl->cnt1, 1u, __ATOMIC_ACQ_REL,
                                          __HIP_MEMORY_SCOPE_AGENT);
    sflag = (old == gridDim.x - 1) ? 1u : 0u;
  }
  __syncthreads();
  if (!sflag) return;

  // ---- select1 (256 threads, 16 bins/thread) ----
  int t = threadIdx.x;
  unsigned hl[16];
  unsigned tot = 0;
#pragma unroll
  for (int j = 0; j < 16; ++j) {
    unsigned s = 0;
    for (int r = 0; r < NREP1; ++r)
      s += aload_u32(&hist1R[(size_t)r * NBINS1 + t * 16 + j]);
    hl[j] = s;
    tot += s;
  }
  __syncthreads();
  h[t] = tot;  // reuse h[0..255] as chunk totals
  __syncthreads();
  for (int off = 1; off < 256; off <<= 1) {  // inclusive suffix scan
    unsigned add = (t + off < 256) ? h[t + off] : 0u;
    __syncthreads();
    h[t] += add;
    __syncthreads();
  }
  unsigned above = (t < 255) ? h[t + 1] : 0u;
  unsigned cum = above;
  for (int j = 15; j >= 0; --j) {
    unsigned nc = cum + hl[j];
    if (cum < K && nc >= K) {  // exactly one (t,j) satisfies globally
      ctl->b1 = (unsigned)(t * 16 + j);
      ctl->r = K - cum;
    }
    cum = nc;
  }
}

// ====== K2: Sgt + refine within b1 + (last block) select2 + finalize =======
__global__ void __launch_bounds__(BLK) k2_kernel(
    const float* __restrict__ preds, const float* __restrict__ gts,
    long long n, Ctl* ctl, const double* __restrict__ blockSums,
    double* __restrict__ blockSgt, unsigned int* __restrict__ hist2R,
    float* __restrict__ sum2R, float* __restrict__ out, unsigned int K) {
  __shared__ unsigned int h2[NBINS2];
  __shared__ float s2[NBINS2];
  __shared__ double wred[4];
  __shared__ unsigned int sflag, sb2, sr2;
  __shared__ double db2sum, db2cnt;
  __shared__ double red5[4][5];
  for (int i = threadIdx.x; i < NBINS2; i += BLK) { h2[i] = 0u; s2[i] = 0.f; }
  __syncthreads();

  unsigned b1 = ctl->b1;  // written last dispatch: plain load fine
  double sgt = 0.0;
  long long n4 = n >> 2;
  const float4* p4 = (const float4*)preds;
  const float4* t4 = (const float4*)gts;
  long long stride = (long long)gridDim.x * BLK;
  long long i0 = (long long)blockIdx.x * BLK + threadIdx.x;

  for (long long i = i0; i < n4; i += stride) {
    float4 p = p4[i];
    float4 t = t4[i];
    float ps[4] = {p.x, p.y, p.z, p.w};
    float ts[4] = {t.x, t.y, t.z, t.w};
#pragma unroll
    for (int j = 0; j < 4; ++j) {
      float v = poly1_val(ps[j], ts[j]);
      unsigned u = __float_as_uint(v);
      unsigned b = u >> 19;
      if (b > b1) {
        sgt += (double)v;
      } else if (b == b1) {
        unsigned key = (u >> 8) & (NBINS2 - 1);  // bits 18:8
        atomicAdd(&h2[key], 1u);
        atomicAdd(&s2[key], v);
      }
    }
  }
  for (long long i = (n4 << 2) + i0; i < n; i += stride) {
    float v = poly1_val(preds[i], gts[i]);
    unsigned u = __float_as_uint(v);
    unsigned b = u >> 19;
    if (b > b1) {
      sgt += (double)v;
    } else if (b == b1) {
      unsigned key = (u >> 8) & (NBINS2 - 1);
      atomicAdd(&h2[key], 1u);
      atomicAdd(&s2[key], v);
    }
  }

#pragma unroll
  for (int off = 32; off; off >>= 1) sgt += __shfl_down(sgt, off, 64);
  if ((threadIdx.x & 63) == 0) wred[threadIdx.x >> 6] = sgt;
  __syncthreads();
  if (threadIdx.x == 0) {
    double v = wred[0] + wred[1] + wred[2] + wred[3];
    // consumed by last block THIS dispatch -> agent-scope atomic store
    __hip_atomic_store(&blockSgt[blockIdx.x], v, __ATOMIC_RELAXED,
                       __HIP_MEMORY_SCOPE_AGENT);
  }

  unsigned int* hd = hist2R + (size_t)(blockIdx.x & (NREP2 - 1)) * NBINS2;
  float* sd = sum2R + (size_t)(blockIdx.x & (NREP2 - 1)) * NBINS2;
  for (int i = threadIdx.x; i < NBINS2; i += BLK) {
    unsigned c = h2[i];
    if (c) atomicAdd(&hd[i], c);
    float sv = s2[i];
    if (sv != 0.f) atomicAdd(&sd[i], sv);
  }

  __threadfence();
  __syncthreads();
  if (threadIdx.x == 0) {
    unsigned old = __hip_atomic_fetch_add(&ctl->cnt2, 1u, __ATOMIC_ACQ_REL,
                                          __HIP_MEMORY_SCOPE_AGENT);
    sflag = (old == gridDim.x - 1) ? 1u : 0u;
  }
  __syncthreads();
  if (!sflag) return;

  // ---- select2 + finalize (256 threads, 8 bins/thread) ----
  int t = threadIdx.x;
  unsigned Kr = ctl->r;
  unsigned hl[8];
  float sl[8];
  unsigned tot = 0;
#pragma unroll
  for (int j = 0; j < 8; ++j) {
    unsigned hs = 0;
    float ss = 0.f;
    for (int r = 0; r < NREP2; ++r) {
      hs += aload_u32(&hist2R[(size_t)r * NBINS2 + t * 8 + j]);
      ss += aload_f32(&sum2R[(size_t)r * NBINS2 + t * 8 + j]);
    }
    hl[j] = hs;
    sl[j] = ss;
    tot += hs;
  }
  __syncthreads();
  h2[t] = tot;  // reuse h2[0..255] as chunk totals
  __syncthreads();
  for (int off = 1; off < 256; off <<= 1) {
    unsigned add = (t + off < 256) ? h2[t + off] : 0u;
    __syncthreads();
    h2[t] += add;
    __syncthreads();
  }
  unsigned above = (t < 255) ? h2[t + 1] : 0u;
  unsigned cum = above;
  for (int j = 7; j >= 0; --j) {
    unsigned nc = cum + hl[j];
    if (cum < Kr && nc >= Kr) {
      sb2 = (unsigned)(t * 8 + j);
      sr2 = Kr - cum;
    }
    cum = nc;
  }
  __syncthreads();
  unsigned b2 = sb2;
  unsigned r2 = sr2;

  double loc = 0.0;
#pragma unroll
  for (int j = 0; j < 8; ++j) {
    int bin = t * 8 + j;
    if (bin > (int)b2) loc += (double)sl[j];
    if (bin == (int)b2) { db2sum = (double)sl[j]; db2cnt = (double)hl[j]; }
  }

  // gather dice partials (prev dispatch: plain loads) + Sgt (this dispatch:
  // agent atomic loads)
  double I = 0, Sp = 0, St = 0, Sg = 0;
  for (int i = t; i < GRID; i += BLK) {
    I += blockSums[i * 3 + 0];
    Sp += blockSums[i * 3 + 1];
    St += blockSums[i * 3 + 2];
    Sg += aload_f64(&blockSgt[i]);
  }
#pragma unroll
  for (int off = 32; off; off >>= 1) {
    loc += __shfl_down(loc, off, 64);
    I += __shfl_down(I, off, 64);
    Sp += __shfl_down(Sp, off, 64);
    St += __shfl_down(St, off, 64);
    Sg += __shfl_down(Sg, off, 64);
  }
  if ((t & 63) == 0) {
    int w = t >> 6;
    red5[w][0] = loc; red5[w][1] = I; red5[w][2] = Sp; red5[w][3] = St;
    red5[w][4] = Sg;
  }
  __syncthreads();
  if (t == 0) {
    double S2 = 0, tI = 0, tSp = 0, tSt = 0, tSg = 0;
#pragma unroll
    for (int w = 0; w < 4; ++w) {
      S2 += red5[w][0]; tI += red5[w][1]; tSp += red5[w][2];
      tSt += red5[w][3]; tSg += red5[w][4];
    }
    // ties in sub-bucket b2 span < 256 ulps: bin average for the r2 remaining
    double avg = db2sum / db2cnt;
    double dice = 1.0 - (2.0 * tI + 1.0) / (tSp + tSt + 1.0);
    double mean_topk = (tSg + S2 + (double)r2 * avg) / (double)K;
    out[0] = (float)(dice + mean_topk);
  }
}

extern "C" void kernel_launch(void* const* d_in, const int* in_sizes, int n_in,
                              void* d_out, int out_size, void* d_ws,
                              size_t ws_size, hipStream_t stream) {
  const float* preds = (const float*)d_in[0];
  const float* gts = (const float*)d_in[1];
  long long n = (long long)in_sizes[0];
  unsigned int K = (unsigned int)(n * 10 / 100);  // matches int(N*10/100)

  char* ws = (char*)d_ws;
  Ctl* ctl = (Ctl*)ws;                                   // @0       (256 B slot)
  double* blockSums = (double*)(ws + 256);               // GRID*3 f64 = 49152
  double* blockSgt = (double*)(ws + 49408);              // GRID f64   = 16384
  unsigned int* hist1R = (unsigned int*)(ws + 65792);    // 16*4096 u32 = 262144
  unsigned int* hist2R = (unsigned int*)(ws + 327936);   // 4*2048 u32  = 32768
  float* sum2R = (float*)(ws + 360704);                  // 4*2048 f32  = 32768
  size_t used = 393472;

  (void)hipMemsetAsync(d_ws, 0, used, stream);

  k1_kernel<<<GRID, BLK, 0, stream>>>(preds, gts, n, ctl, blockSums, hist1R, K);
  k2_kernel<<<GRID, BLK, 0, stream>>>(preds, gts, n, ctl, blockSums, blockSgt,
                                      hist2R, sum2R, (float*)d_out, K);
}

// Round 7
// 246.381 us; speedup vs baseline: 2.4084x; 2.2797x over previous
//
#include <hip/hip_runtime.h>

// DicepolyTopk: dice loss + mean of top-10% poly1-BCE values over N=16.7M fp32.
// Histogram selection on float bit patterns (poly1 >= 0 -> bits order-preserving).
// R7: fused 2-dispatch structure, but with a cache-op-free arrival protocol.
// R5/R6's per-wave __threadfence() (buffer_wbl2+buffer_inv per wave) and
// ACQ_REL arrival RMW caused ~200us of L2-maintenance serialization. Now:
// __syncthreads() drains vmcnt(0) per wave (hist atomics globally performed),
// then ONE relaxed agent-scope RMW per block. Tail reads use agent-scope
// atomic loads (coherence-point path, immune to stale L1/L2).

#define NBINS1 4096
#define NBINS2 2048
#define NREP1 16
#define NREP2 4
#define GRID 2048
#define BLK 256
#define POLY_EPS 3.1f
#define LN2F 0.69314718056f

struct Ctl {
  unsigned int b1;    // L1 bucket containing the k-th largest value
  unsigned int r;     // k - count(strictly greater L1 buckets)
  unsigned int cnt1;  // arrival counter kernel 1
  unsigned int cnt2;  // arrival counter kernel 2
};

// bce in log2 domain: a2=log2(p), b2=log2(1-p); bce2 = -(b2 + t*(a2-b2))
// bce = bce2*ln2 ; pt = 2^(-bce2) ; poly1 = bce + (1-pt)*eps, clamped >= 0.
// Must be bit-identical between K1 and K2 (same code, deterministic).
__device__ __forceinline__ float poly1_val(float p, float t) {
  float a2 = __builtin_amdgcn_logf(p);         // v_log_f32: log2(p)
  float b2 = __builtin_amdgcn_logf(1.0f - p);  // log2(1-p)
  float bce2 = -(b2 + t * (a2 - b2));
  float pt = __builtin_amdgcn_exp2f(-bce2);    // v_exp_f32: 2^(-bce2)
  float v = bce2 * LN2F + (1.0f - pt) * POLY_EPS;
  return v > 0.0f ? v : 0.0f;
}

__device__ __forceinline__ unsigned int aload_u32(const unsigned int* p) {
  return __hip_atomic_load(p, __ATOMIC_RELAXED, __HIP_MEMORY_SCOPE_AGENT);
}
__device__ __forceinline__ float aload_f32(const float* p) {
  return __hip_atomic_load(p, __ATOMIC_RELAXED, __HIP_MEMORY_SCOPE_AGENT);
}
__device__ __forceinline__ double aload_f64(const double* p) {
  return __hip_atomic_load(p, __ATOMIC_RELAXED, __HIP_MEMORY_SCOPE_AGENT);
}

// ============ K1: dice sums + L1 histogram + (last block) select1 ==========
__global__ void __launch_bounds__(BLK) k1_kernel(
    const float* __restrict__ preds, const float* __restrict__ gts,
    long long n, Ctl* ctl, double* __restrict__ blockSums,
    unsigned int* __restrict__ hist1R, unsigned int K) {
  __shared__ unsigned int h[NBINS1];
  __shared__ double wred[4][3];
  __shared__ unsigned int sflag;
  for (int i = threadIdx.x; i < NBINS1; i += BLK) h[i] = 0u;
  __syncthreads();

  float I = 0.f, Sp = 0.f, St = 0.f;
  long long n4 = n >> 2;
  const float4* p4 = (const float4*)preds;
  const float4* t4 = (const float4*)gts;
  long long stride = (long long)gridDim.x * BLK;
  long long i0 = (long long)blockIdx.x * BLK + threadIdx.x;

  for (long long i = i0; i < n4; i += stride) {
    float4 p = p4[i];
    float4 t = t4[i];
    float ps[4] = {p.x, p.y, p.z, p.w};
    float ts[4] = {t.x, t.y, t.z, t.w};
#pragma unroll
    for (int j = 0; j < 4; ++j) {
      float pp = ps[j], tt = ts[j];
      I += pp * tt;
      Sp += pp;
      St += tt;
      float v = poly1_val(pp, tt);
      atomicAdd(&h[__float_as_uint(v) >> 19], 1u);
    }
  }
  for (long long i = (n4 << 2) + i0; i < n; i += stride) {
    float pp = preds[i], tt = gts[i];
    I += pp * tt; Sp += pp; St += tt;
    float v = poly1_val(pp, tt);
    atomicAdd(&h[__float_as_uint(v) >> 19], 1u);
  }

  // block dice reduce -> one plain store (consumed next dispatch, no atomics)
  double dI = I, dSp = Sp, dSt = St;
#pragma unroll
  for (int off = 32; off; off >>= 1) {
    dI += __shfl_down(dI, off, 64);
    dSp += __shfl_down(dSp, off, 64);
    dSt += __shfl_down(dSt, off, 64);
  }
  if ((threadIdx.x & 63) == 0) {
    int w = threadIdx.x >> 6;
    wred[w][0] = dI; wred[w][1] = dSp; wred[w][2] = dSt;
  }
  __syncthreads();
  if (threadIdx.x == 0) {
    double a = 0, b = 0, c = 0;
#pragma unroll
    for (int w = 0; w < 4; ++w) { a += wred[w][0]; b += wred[w][1]; c += wred[w][2]; }
    blockSums[blockIdx.x * 3 + 0] = a;
    blockSums[blockIdx.x * 3 + 1] = b;
    blockSums[blockIdx.x * 3 + 2] = c;
  }

  // flush LDS hist to one of NREP1 replicas (device-scope atomics)
  unsigned int* dst = hist1R + (size_t)(blockIdx.x & (NREP1 - 1)) * NBINS1;
  for (int i = threadIdx.x; i < NBINS1; i += BLK) {
    unsigned c = h[i];
    if (c) atomicAdd(&dst[i], c);
  }

  // arrival: __syncthreads drains vmcnt(0) per wave -> all hist atomics are
  // globally performed. One RELAXED agent RMW per block (no cache-op storm).
  __syncthreads();
  if (threadIdx.x == 0) {
    unsigned old = __hip_atomic_fetch_add(&ctl->cnt1, 1u, __ATOMIC_RELAXED,
                                          __HIP_MEMORY_SCOPE_AGENT);
    sflag = (old == gridDim.x - 1) ? 1u : 0u;
  }
  __syncthreads();
  if (!sflag) return;
  if (threadIdx.x == 0)  // belt-and-braces acquire before tail reads
    (void)__hip_atomic_load(&ctl->cnt1, __ATOMIC_ACQUIRE,
                            __HIP_MEMORY_SCOPE_AGENT);
  __syncthreads();

  // ---- select1 (256 threads, 16 bins/thread) ----
  int t = threadIdx.x;
  unsigned hl[16];
  unsigned tot = 0;
#pragma unroll
  for (int j = 0; j < 16; ++j) {
    unsigned s = 0;
    for (int r = 0; r < NREP1; ++r)
      s += aload_u32(&hist1R[(size_t)r * NBINS1 + t * 16 + j]);
    hl[j] = s;
    tot += s;
  }
  __syncthreads();
  h[t] = tot;  // reuse h[0..255] as chunk totals
  __syncthreads();
  for (int off = 1; off < 256; off <<= 1) {  // inclusive suffix scan
    unsigned add = (t + off < 256) ? h[t + off] : 0u;
    __syncthreads();
    h[t] += add;
    __syncthreads();
  }
  unsigned above = (t < 255) ? h[t + 1] : 0u;
  unsigned cum = above;
  for (int j = 15; j >= 0; --j) {
    unsigned nc = cum + hl[j];
    if (cum < K && nc >= K) {  // exactly one (t,j) satisfies globally
      ctl->b1 = (unsigned)(t * 16 + j);
      ctl->r = K - cum;
    }
    cum = nc;
  }
}

// ====== K2: Sgt + refine within b1 + (last block) select2 + finalize =======
__global__ void __launch_bounds__(BLK) k2_kernel(
    const float* __restrict__ preds, const float* __restrict__ gts,
    long long n, Ctl* ctl, const double* __restrict__ blockSums,
    double* __restrict__ blockSgt, unsigned int* __restrict__ hist2R,
    float* __restrict__ sum2R, float* __restrict__ out, unsigned int K) {
  __shared__ unsigned int h2[NBINS2];
  __shared__ float s2[NBINS2];
  __shared__ double wred[4];
  __shared__ unsigned int sflag, sb2, sr2;
  __shared__ double db2sum, db2cnt;
  __shared__ double red5[4][5];
  for (int i = threadIdx.x; i < NBINS2; i += BLK) { h2[i] = 0u; s2[i] = 0.f; }
  __syncthreads();

  unsigned b1 = ctl->b1;  // written last dispatch: plain load fine
  double sgt = 0.0;
  long long n4 = n >> 2;
  const float4* p4 = (const float4*)preds;
  const float4* t4 = (const float4*)gts;
  long long stride = (long long)gridDim.x * BLK;
  long long i0 = (long long)blockIdx.x * BLK + threadIdx.x;

  for (long long i = i0; i < n4; i += stride) {
    float4 p = p4[i];
    float4 t = t4[i];
    float ps[4] = {p.x, p.y, p.z, p.w};
    float ts[4] = {t.x, t.y, t.z, t.w};
#pragma unroll
    for (int j = 0; j < 4; ++j) {
      float v = poly1_val(ps[j], ts[j]);
      unsigned u = __float_as_uint(v);
      unsigned b = u >> 19;
      if (b > b1) {
        sgt += (double)v;
      } else if (b == b1) {
        unsigned key = (u >> 8) & (NBINS2 - 1);  // bits 18:8
        atomicAdd(&h2[key], 1u);
        atomicAdd(&s2[key], v);
      }
    }
  }
  for (long long i = (n4 << 2) + i0; i < n; i += stride) {
    float v = poly1_val(preds[i], gts[i]);
    unsigned u = __float_as_uint(v);
    unsigned b = u >> 19;
    if (b > b1) {
      sgt += (double)v;
    } else if (b == b1) {
      unsigned key = (u >> 8) & (NBINS2 - 1);
      atomicAdd(&h2[key], 1u);
      atomicAdd(&s2[key], v);
    }
  }

#pragma unroll
  for (int off = 32; off; off >>= 1) sgt += __shfl_down(sgt, off, 64);
  if ((threadIdx.x & 63) == 0) wred[threadIdx.x >> 6] = sgt;
  __syncthreads();
  if (threadIdx.x == 0) {
    double v = wred[0] + wred[1] + wred[2] + wred[3];
    // consumed by last block THIS dispatch -> agent-scope atomic store
    __hip_atomic_store(&blockSgt[blockIdx.x], v, __ATOMIC_RELAXED,
                       __HIP_MEMORY_SCOPE_AGENT);
  }

  unsigned int* hd = hist2R + (size_t)(blockIdx.x & (NREP2 - 1)) * NBINS2;
  float* sd = sum2R + (size_t)(blockIdx.x & (NREP2 - 1)) * NBINS2;
  for (int i = threadIdx.x; i < NBINS2; i += BLK) {
    unsigned c = h2[i];
    if (c) atomicAdd(&hd[i], c);
    float sv = s2[i];
    if (sv != 0.f) atomicAdd(&sd[i], sv);
  }

  __syncthreads();  // drains vmcnt(0): hist/sum atomics + Sgt store performed
  if (threadIdx.x == 0) {
    unsigned old = __hip_atomic_fetch_add(&ctl->cnt2, 1u, __ATOMIC_RELAXED,
                                          __HIP_MEMORY_SCOPE_AGENT);
    sflag = (old == gridDim.x - 1) ? 1u : 0u;
  }
  __syncthreads();
  if (!sflag) return;
  if (threadIdx.x == 0)
    (void)__hip_atomic_load(&ctl->cnt2, __ATOMIC_ACQUIRE,
                            __HIP_MEMORY_SCOPE_AGENT);
  __syncthreads();

  // ---- select2 + finalize (256 threads, 8 bins/thread) ----
  int t = threadIdx.x;
  unsigned Kr = ctl->r;
  unsigned hl[8];
  float sl[8];
  unsigned tot = 0;
#pragma unroll
  for (int j = 0; j < 8; ++j) {
    unsigned hs = 0;
    float ss = 0.f;
    for (int r = 0; r < NREP2; ++r) {
      hs += aload_u32(&hist2R[(size_t)r * NBINS2 + t * 8 + j]);
      ss += aload_f32(&sum2R[(size_t)r * NBINS2 + t * 8 + j]);
    }
    hl[j] = hs;
    sl[j] = ss;
    tot += hs;
  }
  __syncthreads();
  h2[t] = tot;  // reuse h2[0..255] as chunk totals
  __syncthreads();
  for (int off = 1; off < 256; off <<= 1) {
    unsigned add = (t + off < 256) ? h2[t + off] : 0u;
    __syncthreads();
    h2[t] += add;
    __syncthreads();
  }
  unsigned above = (t < 255) ? h2[t + 1] : 0u;
  unsigned cum = above;
  for (int j = 7; j >= 0; --j) {
    unsigned nc = cum + hl[j];
    if (cum < Kr && nc >= Kr) {
      sb2 = (unsigned)(t * 8 + j);
      sr2 = Kr - cum;
    }
    cum = nc;
  }
  __syncthreads();
  unsigned b2 = sb2;
  unsigned r2 = sr2;

  double loc = 0.0;
#pragma unroll
  for (int j = 0; j < 8; ++j) {
    int bin = t * 8 + j;
    if (bin > (int)b2) loc += (double)sl[j];
    if (bin == (int)b2) { db2sum = (double)sl[j]; db2cnt = (double)hl[j]; }
  }

  // gather dice partials (prev dispatch: plain loads) + Sgt (this dispatch:
  // agent atomic loads)
  double I = 0, Sp = 0, St = 0, Sg = 0;
  for (int i = t; i < GRID; i += BLK) {
    I += blockSums[i * 3 + 0];
    Sp += blockSums[i * 3 + 1];
    St += blockSums[i * 3 + 2];
    Sg += aload_f64(&blockSgt[i]);
  }
#pragma unroll
  for (int off = 32; off; off >>= 1) {
    loc += __shfl_down(loc, off, 64);
    I += __shfl_down(I, off, 64);
    Sp += __shfl_down(Sp, off, 64);
    St += __shfl_down(St, off, 64);
    Sg += __shfl_down(Sg, off, 64);
  }
  if ((t & 63) == 0) {
    int w = t >> 6;
    red5[w][0] = loc; red5[w][1] = I; red5[w][2] = Sp; red5[w][3] = St;
    red5[w][4] = Sg;
  }
  __syncthreads();
  if (t == 0) {
    double S2 = 0, tI = 0, tSp = 0, tSt = 0, tSg = 0;
#pragma unroll
    for (int w = 0; w < 4; ++w) {
      S2 += red5[w][0]; tI += red5[w][1]; tSp += red5[w][2];
      tSt += red5[w][3]; tSg += red5[w][4];
    }
    // ties in sub-bucket b2 span < 256 ulps: bin average for the r2 remaining
    double avg = db2sum / db2cnt;
    double dice = 1.0 - (2.0 * tI + 1.0) / (tSp + tSt + 1.0);
    double mean_topk = (tSg + S2 + (double)r2 * avg) / (double)K;
    out[0] = (float)(dice + mean_topk);
  }
}

extern "C" void kernel_launch(void* const* d_in, const int* in_sizes, int n_in,
                              void* d_out, int out_size, void* d_ws,
                              size_t ws_size, hipStream_t stream) {
  const float* preds = (const float*)d_in[0];
  const float* gts = (const float*)d_in[1];
  long long n = (long long)in_sizes[0];
  unsigned int K = (unsigned int)(n * 10 / 100);  // matches int(N*10/100)

  char* ws = (char*)d_ws;
  Ctl* ctl = (Ctl*)ws;                                   // @0       (256 B slot)
  double* blockSums = (double*)(ws + 256);               // GRID*3 f64 = 49152
  double* blockSgt = (double*)(ws + 49408);              // GRID f64   = 16384
  unsigned int* hist1R = (unsigned int*)(ws + 65792);    // 16*4096 u32 = 262144
  unsigned int* hist2R = (unsigned int*)(ws + 327936);   // 4*2048 u32  = 32768
  float* sum2R = (float*)(ws + 360704);                  // 4*2048 f32  = 32768
  size_t used = 393472;

  (void)hipMemsetAsync(d_ws, 0, used, stream);

  k1_kernel<<<GRID, BLK, 0, stream>>>(preds, gts, n, ctl, blockSums, hist1R, K);
  k2_kernel<<<GRID, BLK, 0, stream>>>(preds, gts, n, ctl, blockSums, blockSgt,
                                      hist2R, sum2R, (float*)d_out, K);
}

// Round 8
// 228.358 us; speedup vs baseline: 2.5985x; 1.0789x over previous
//
#include <hip/hip_runtime.h>

// DicepolyTopk: dice loss + mean of top-10% poly1-BCE values over N=16.7M fp32.
// Histogram selection on float bit patterns (poly1 >= 0 -> bits order-preserving).
// R8: R7 + (a) hierarchical arrival -- 64 padded local counters, group-last
// promotes to global counter; kills the 2048 same-address RMW serialization
// (~41 us/kernel). (b) 2x unrolled main loops (4 independent 16B loads/thread)
// for the L3-latency-bound regime (FETCH shows inputs fully L3-resident).

#define NBINS1 4096
#define NBINS2 2048
#define NREP1 16
#define NREP2 4
#define GRID 2048
#define BLK 256
#define NLOC 64                 // local arrival groups
#define GPB (GRID / NLOC)       // blocks per group = 32
#define CTR_STRIDE 32           // u32 stride -> one 128B line per counter
#define POLY_EPS 3.1f
#define LN2F 0.69314718056f

struct Ctl {
  unsigned int b1;    // L1 bucket containing the k-th largest value
  unsigned int r;     // k - count(strictly greater L1 buckets)
  unsigned int cnt1;  // global arrival counter kernel 1
  unsigned int cnt2;  // global arrival counter kernel 2
};

// bce in log2 domain: a2=log2(p), b2=log2(1-p); bce2 = -(b2 + t*(a2-b2))
// bce = bce2*ln2 ; pt = 2^(-bce2) ; poly1 = bce + (1-pt)*eps, clamped >= 0.
// Must be bit-identical between K1 and K2 (same code, deterministic).
__device__ __forceinline__ float poly1_val(float p, float t) {
  float a2 = __builtin_amdgcn_logf(p);         // v_log_f32: log2(p)
  float b2 = __builtin_amdgcn_logf(1.0f - p);  // log2(1-p)
  float bce2 = -(b2 + t * (a2 - b2));
  float pt = __builtin_amdgcn_exp2f(-bce2);    // v_exp_f32: 2^(-bce2)
  float v = bce2 * LN2F + (1.0f - pt) * POLY_EPS;
  return v > 0.0f ? v : 0.0f;
}

__device__ __forceinline__ unsigned int aload_u32(const unsigned int* p) {
  return __hip_atomic_load(p, __ATOMIC_RELAXED, __HIP_MEMORY_SCOPE_AGENT);
}
__device__ __forceinline__ float aload_f32(const float* p) {
  return __hip_atomic_load(p, __ATOMIC_RELAXED, __HIP_MEMORY_SCOPE_AGENT);
}
__device__ __forceinline__ double aload_f64(const double* p) {
  return __hip_atomic_load(p, __ATOMIC_RELAXED, __HIP_MEMORY_SCOPE_AGENT);
}

// Hierarchical arrival. Preconditions: __syncthreads() already executed (all
// waves' vmcnt drained -> their global atomics are performed). Returns true in
// ALL threads of exactly the globally-last block.
__device__ __forceinline__ bool arrive_last(unsigned int* locCtr,
                                            unsigned int* gCtr,
                                            unsigned int* sflag_lds) {
  if (threadIdx.x == 0) {
    unsigned g = blockIdx.x & (NLOC - 1);
    unsigned old = __hip_atomic_fetch_add(&locCtr[g * CTR_STRIDE], 1u,
                                          __ATOMIC_RELAXED,
                                          __HIP_MEMORY_SCOPE_AGENT);
    unsigned f = 0u;
    if (old == GPB - 1) {  // group complete -> promote
      unsigned og = __hip_atomic_fetch_add(gCtr, 1u, __ATOMIC_RELAXED,
                                           __HIP_MEMORY_SCOPE_AGENT);
      f = (og == NLOC - 1) ? 1u : 0u;
    }
    *sflag_lds = f;
  }
  __syncthreads();
  return *sflag_lds != 0u;
}

// ============ K1: dice sums + L1 histogram + (last block) select1 ==========
__global__ void __launch_bounds__(BLK) k1_kernel(
    const float* __restrict__ preds, const float* __restrict__ gts,
    long long n, Ctl* ctl, unsigned int* __restrict__ loc1,
    double* __restrict__ blockSums, unsigned int* __restrict__ hist1R,
    unsigned int K) {
  __shared__ unsigned int h[NBINS1];
  __shared__ double wred[4][3];
  __shared__ unsigned int sflag;
  for (int i = threadIdx.x; i < NBINS1; i += BLK) h[i] = 0u;
  __syncthreads();

  float I = 0.f, Sp = 0.f, St = 0.f;
  long long n8 = n >> 3;
  const float4* p4 = (const float4*)preds;
  const float4* t4 = (const float4*)gts;
  long long stride = (long long)gridDim.x * BLK;
  long long i0 = (long long)blockIdx.x * BLK + threadIdx.x;

  for (long long i = i0; i < n8; i += stride) {
    float4 pa = p4[2 * i];
    float4 pb = p4[2 * i + 1];
    float4 ta = t4[2 * i];
    float4 tb = t4[2 * i + 1];
    float ps[8] = {pa.x, pa.y, pa.z, pa.w, pb.x, pb.y, pb.z, pb.w};
    float ts[8] = {ta.x, ta.y, ta.z, ta.w, tb.x, tb.y, tb.z, tb.w};
#pragma unroll
    for (int j = 0; j < 8; ++j) {
      float pp = ps[j], tt = ts[j];
      I += pp * tt;
      Sp += pp;
      St += tt;
      float v = poly1_val(pp, tt);
      atomicAdd(&h[__float_as_uint(v) >> 19], 1u);
    }
  }
  for (long long i = (n8 << 3) + i0; i < n; i += stride) {
    float pp = preds[i], tt = gts[i];
    I += pp * tt; Sp += pp; St += tt;
    float v = poly1_val(pp, tt);
    atomicAdd(&h[__float_as_uint(v) >> 19], 1u);
  }

  // block dice reduce -> one plain store (consumed next dispatch, no atomics)
  double dI = I, dSp = Sp, dSt = St;
#pragma unroll
  for (int off = 32; off; off >>= 1) {
    dI += __shfl_down(dI, off, 64);
    dSp += __shfl_down(dSp, off, 64);
    dSt += __shfl_down(dSt, off, 64);
  }
  if ((threadIdx.x & 63) == 0) {
    int w = threadIdx.x >> 6;
    wred[w][0] = dI; wred[w][1] = dSp; wred[w][2] = dSt;
  }
  __syncthreads();
  if (threadIdx.x == 0) {
    double a = 0, b = 0, c = 0;
#pragma unroll
    for (int w = 0; w < 4; ++w) { a += wred[w][0]; b += wred[w][1]; c += wred[w][2]; }
    blockSums[blockIdx.x * 3 + 0] = a;
    blockSums[blockIdx.x * 3 + 1] = b;
    blockSums[blockIdx.x * 3 + 2] = c;
  }

  // flush LDS hist to one of NREP1 replicas (device-scope atomics)
  unsigned int* dst = hist1R + (size_t)(blockIdx.x & (NREP1 - 1)) * NBINS1;
  for (int i = threadIdx.x; i < NBINS1; i += BLK) {
    unsigned c = h[i];
    if (c) atomicAdd(&dst[i], c);
  }

  __syncthreads();  // drains vmcnt(0): all hist atomics globally performed
  if (!arrive_last(loc1, &ctl->cnt1, &sflag)) return;

  // ---- select1 (256 threads, 16 bins/thread) ----
  int t = threadIdx.x;
  unsigned hl[16];
  unsigned tot = 0;
#pragma unroll
  for (int j = 0; j < 16; ++j) {
    unsigned s = 0;
    for (int r = 0; r < NREP1; ++r)
      s += aload_u32(&hist1R[(size_t)r * NBINS1 + t * 16 + j]);
    hl[j] = s;
    tot += s;
  }
  __syncthreads();
  h[t] = tot;  // reuse h[0..255] as chunk totals
  __syncthreads();
  for (int off = 1; off < 256; off <<= 1) {  // inclusive suffix scan
    unsigned add = (t + off < 256) ? h[t + off] : 0u;
    __syncthreads();
    h[t] += add;
    __syncthreads();
  }
  unsigned above = (t < 255) ? h[t + 1] : 0u;
  unsigned cum = above;
  for (int j = 15; j >= 0; --j) {
    unsigned nc = cum + hl[j];
    if (cum < K && nc >= K) {  // exactly one (t,j) satisfies globally
      ctl->b1 = (unsigned)(t * 16 + j);
      ctl->r = K - cum;
    }
    cum = nc;
  }
}

// ====== K2: Sgt + refine within b1 + (last block) select2 + finalize =======
__global__ void __launch_bounds__(BLK) k2_kernel(
    const float* __restrict__ preds, const float* __restrict__ gts,
    long long n, Ctl* ctl, unsigned int* __restrict__ loc2,
    const double* __restrict__ blockSums, double* __restrict__ blockSgt,
    unsigned int* __restrict__ hist2R, float* __restrict__ sum2R,
    float* __restrict__ out, unsigned int K) {
  __shared__ unsigned int h2[NBINS2];
  __shared__ float s2[NBINS2];
  __shared__ double wred[4];
  __shared__ unsigned int sflag, sb2, sr2;
  __shared__ double db2sum, db2cnt;
  __shared__ double red5[4][5];
  for (int i = threadIdx.x; i < NBINS2; i += BLK) { h2[i] = 0u; s2[i] = 0.f; }
  __syncthreads();

  unsigned b1 = ctl->b1;  // written last dispatch: plain load fine
  double sgt = 0.0;
  long long n8 = n >> 3;
  const float4* p4 = (const float4*)preds;
  const float4* t4 = (const float4*)gts;
  long long stride = (long long)gridDim.x * BLK;
  long long i0 = (long long)blockIdx.x * BLK + threadIdx.x;

  for (long long i = i0; i < n8; i += stride) {
    float4 pa = p4[2 * i];
    float4 pb = p4[2 * i + 1];
    float4 ta = t4[2 * i];
    float4 tb = t4[2 * i + 1];
    float ps[8] = {pa.x, pa.y, pa.z, pa.w, pb.x, pb.y, pb.z, pb.w};
    float ts[8] = {ta.x, ta.y, ta.z, ta.w, tb.x, tb.y, tb.z, tb.w};
#pragma unroll
    for (int j = 0; j < 8; ++j) {
      float v = poly1_val(ps[j], ts[j]);
      unsigned u = __float_as_uint(v);
      unsigned b = u >> 19;
      if (b > b1) {
        sgt += (double)v;
      } else if (b == b1) {
        unsigned key = (u >> 8) & (NBINS2 - 1);  // bits 18:8
        atomicAdd(&h2[key], 1u);
        atomicAdd(&s2[key], v);
      }
    }
  }
  for (long long i = (n8 << 3) + i0; i < n; i += stride) {
    float v = poly1_val(preds[i], gts[i]);
    unsigned u = __float_as_uint(v);
    unsigned b = u >> 19;
    if (b > b1) {
      sgt += (double)v;
    } else if (b == b1) {
      unsigned key = (u >> 8) & (NBINS2 - 1);
      atomicAdd(&h2[key], 1u);
      atomicAdd(&s2[key], v);
    }
  }

#pragma unroll
  for (int off = 32; off; off >>= 1) sgt += __shfl_down(sgt, off, 64);
  if ((threadIdx.x & 63) == 0) wred[threadIdx.x >> 6] = sgt;
  __syncthreads();
  if (threadIdx.x == 0) {
    double v = wred[0] + wred[1] + wred[2] + wred[3];
    // consumed by last block THIS dispatch -> agent-scope atomic store
    __hip_atomic_store(&blockSgt[blockIdx.x], v, __ATOMIC_RELAXED,
                       __HIP_MEMORY_SCOPE_AGENT);
  }

  unsigned int* hd = hist2R + (size_t)(blockIdx.x & (NREP2 - 1)) * NBINS2;
  float* sd = sum2R + (size_t)(blockIdx.x & (NREP2 - 1)) * NBINS2;
  for (int i = threadIdx.x; i < NBINS2; i += BLK) {
    unsigned c = h2[i];
    if (c) atomicAdd(&hd[i], c);
    float sv = s2[i];
    if (sv != 0.f) atomicAdd(&sd[i], sv);
  }

  __syncthreads();  // drains vmcnt(0): hist/sum atomics + Sgt store performed
  if (!arrive_last(loc2, &ctl->cnt2, &sflag)) return;

  // ---- select2 + finalize (256 threads, 8 bins/thread) ----
  int t = threadIdx.x;
  unsigned Kr = ctl->r;
  unsigned hl[8];
  float sl[8];
  unsigned tot = 0;
#pragma unroll
  for (int j = 0; j < 8; ++j) {
    unsigned hs = 0;
    float ss = 0.f;
    for (int r = 0; r < NREP2; ++r) {
      hs += aload_u32(&hist2R[(size_t)r * NBINS2 + t * 8 + j]);
      ss += aload_f32(&sum2R[(size_t)r * NBINS2 + t * 8 + j]);
    }
    hl[j] = hs;
    sl[j] = ss;
    tot += hs;
  }
  __syncthreads();
  h2[t] = tot;  // reuse h2[0..255] as chunk totals
  __syncthreads();
  for (int off = 1; off < 256; off <<= 1) {
    unsigned add = (t + off < 256) ? h2[t + off] : 0u;
    __syncthreads();
    h2[t] += add;
    __syncthreads();
  }
  unsigned above = (t < 255) ? h2[t + 1] : 0u;
  unsigned cum = above;
  for (int j = 7; j >= 0; --j) {
    unsigned nc = cum + hl[j];
    if (cum < Kr && nc >= Kr) {
      sb2 = (unsigned)(t * 8 + j);
      sr2 = Kr - cum;
    }
    cum = nc;
  }
  __syncthreads();
  unsigned b2 = sb2;
  unsigned r2 = sr2;

  double loc = 0.0;
#pragma unroll
  for (int j = 0; j < 8; ++j) {
    int bin = t * 8 + j;
    if (bin > (int)b2) loc += (double)sl[j];
    if (bin == (int)b2) { db2sum = (double)sl[j]; db2cnt = (double)hl[j]; }
  }

  // gather dice partials (prev dispatch: plain loads) + Sgt (this dispatch:
  // agent atomic loads)
  double I = 0, Sp = 0, St = 0, Sg = 0;
  for (int i = t; i < GRID; i += BLK) {
    I += blockSums[i * 3 + 0];
    Sp += blockSums[i * 3 + 1];
    St += blockSums[i * 3 + 2];
    Sg += aload_f64(&blockSgt[i]);
  }
#pragma unroll
  for (int off = 32; off; off >>= 1) {
    loc += __shfl_down(loc, off, 64);
    I += __shfl_down(I, off, 64);
    Sp += __shfl_down(Sp, off, 64);
    St += __shfl_down(St, off, 64);
    Sg += __shfl_down(Sg, off, 64);
  }
  if ((t & 63) == 0) {
    int w = t >> 6;
    red5[w][0] = loc; red5[w][1] = I; red5[w][2] = Sp; red5[w][3] = St;
    red5[w][4] = Sg;
  }
  __syncthreads();
  if (t == 0) {
    double S2 = 0, tI = 0, tSp = 0, tSt = 0, tSg = 0;
#pragma unroll
    for (int w = 0; w < 4; ++w) {
      S2 += red5[w][0]; tI += red5[w][1]; tSp += red5[w][2];
      tSt += red5[w][3]; tSg += red5[w][4];
    }
    // ties in sub-bucket b2 span < 256 ulps: bin average for the r2 remaining
    double avg = db2sum / db2cnt;
    double dice = 1.0 - (2.0 * tI + 1.0) / (tSp + tSt + 1.0);
    double mean_topk = (tSg + S2 + (double)r2 * avg) / (double)K;
    out[0] = (float)(dice + mean_topk);
  }
}

extern "C" void kernel_launch(void* const* d_in, const int* in_sizes, int n_in,
                              void* d_out, int out_size, void* d_ws,
                              size_t ws_size, hipStream_t stream) {
  const float* preds = (const float*)d_in[0];
  const float* gts = (const float*)d_in[1];
  long long n = (long long)in_sizes[0];
  unsigned int K = (unsigned int)(n * 10 / 100);  // matches int(N*10/100)

  char* ws = (char*)d_ws;
  Ctl* ctl = (Ctl*)ws;                                   // @0       (256 B slot)
  unsigned int* loc1 = (unsigned int*)(ws + 256);        // 64*128B = 8192
  unsigned int* loc2 = (unsigned int*)(ws + 8448);       // 64*128B = 8192
  double* blockSums = (double*)(ws + 16640);             // GRID*3 f64 = 49152
  double* blockSgt = (double*)(ws + 65792);              // GRID f64   = 16384
  unsigned int* hist1R = (unsigned int*)(ws + 82176);    // 16*4096 u32 = 262144
  unsigned int* hist2R = (unsigned int*)(ws + 344320);   // 4*2048 u32  = 32768
  float* sum2R = (float*)(ws + 377088);                  // 4*2048 f32  = 32768
  size_t used = 409856;

  (void)hipMemsetAsync(d_ws, 0, used, stream);

  k1_kernel<<<GRID, BLK, 0, stream>>>(preds, gts, n, ctl, loc1, blockSums,
                                      hist1R, K);
  k2_kernel<<<GRID, BLK, 0, stream>>>(preds, gts, n, ctl, loc2, blockSums,
                                      blockSgt, hist2R, sum2R, (float*)d_out, K);
}